// Round 4
// baseline (1047.567 us; speedup 1.0000x reference)
//
#include <hip/hip_runtime.h>
#include <cstdint>
#include <cstddef>

#define B_ 2048
#define N_ 62
#define FIN_ 128
#define HID_ 512
#define HEADS_ 8
#define FOUT_ 64
#define LAYERS_ 3
#define M_ (B_*N_)           // 126976
#define L2E 1.44269504f

typedef __bf16 bf16x8 __attribute__((ext_vector_type(8)));
typedef __bf16 bf16x4 __attribute__((ext_vector_type(4)));
typedef float  f32x4  __attribute__((ext_vector_type(4)));
typedef unsigned short u16;

static __device__ __forceinline__ u16 f2bf(float f) {
    union { float f; uint32_t u; } v; v.f = f;
    uint32_t u = v.u;
    return (u16)((u + 0x7fffu + ((u >> 16) & 1u)) >> 16);
}
static __device__ __forceinline__ float bf2f(u16 s) {
    union { uint32_t u; float f; } v; v.u = ((uint32_t)s) << 16;
    return v.f;
}

// ---------------------------------------------------------------------------
// xb = BN(x) cast to bf16
// ---------------------------------------------------------------------------
__global__ __launch_bounds__(256) void bn_cast(
    const float* __restrict__ x, const float* __restrict__ bng,
    const float* __restrict__ bnb, const float* __restrict__ bnm,
    const float* __restrict__ bnv, u16* __restrict__ xb)
{
    int g = blockIdx.x * 256 + threadIdx.x;
    if (g >= M_ * (FIN_ / 4)) return;
    int row = g >> 5;
    int n = row % N_;
    float s = bng[n] * rsqrtf(bnv[n] + 1e-5f);
    float sh = bnb[n] - bnm[n] * s;
    float4 v = ((const float4*)x)[g];
    ushort4 o;
    o.x = f2bf(v.x * s + sh);
    o.y = f2bf(v.y * s + sh);
    o.z = f2bf(v.z * s + sh);
    o.w = f2bf(v.w * s + sh);
    ((ushort4*)xb)[g] = o;
}

// ---------------------------------------------------------------------------
// Pack transposed bf16 weights: wmlp_t[n][k]; wgat_t[l][n][k] (n = head*64+d)
// ---------------------------------------------------------------------------
__global__ __launch_bounds__(256) void repack_w(
    const float* __restrict__ Wm, const float* __restrict__ Wg,
    u16* __restrict__ wmlp_t, u16* __restrict__ wgat_t)
{
    int idx = blockIdx.x * 256 + threadIdx.x;
    const int T1 = HID_ * FIN_;
    const int T2 = LAYERS_ * HID_ * HID_;
    if (idx < T1) {
        int n = idx / FIN_, k = idx % FIN_;
        wmlp_t[idx] = f2bf(Wm[k * HID_ + n]);
    } else if (idx < T1 + T2) {
        int j = idx - T1;
        int l = j / (HID_ * HID_);
        int r = j % (HID_ * HID_);
        int n = r / HID_, k = r % HID_;
        wgat_t[j] = f2bf(Wg[(((size_t)(l * HEADS_ + (n >> 6))) * HID_ + k) * FOUT_ + (n & 63)]);
    }
}

// ---------------------------------------------------------------------------
// adjacency -> per-row 64-bit masks, one block per graph
// ---------------------------------------------------------------------------
__global__ __launch_bounds__(256) void build_masks(
    const int* __restrict__ adj, uint64_t* __restrict__ masks)
{
    __shared__ uint32_t m32[128];
    const int b = blockIdx.x, tid = threadIdx.x;
    if (tid < 128) m32[tid] = 0;
    __syncthreads();
    const int* a = adj + (size_t)b * N_ * N_;
    for (int idx = tid; idx < N_ * N_; idx += 256) {
        int i = idx / N_, j = idx % N_;
        if (a[idx] > 0) atomicOr(&m32[i * 2 + (j >> 5)], 1u << (j & 31));
    }
    __syncthreads();
    if (tid < 128) ((uint32_t*)(masks + (size_t)b * 64))[tid] = m32[tid];
}

// ---------------------------------------------------------------------------
// bf16 MFMA GEMM for the MLP (K=128), LDS-staged coalesced epilogue.
// ---------------------------------------------------------------------------
#define CS_STRIDE 136
__global__ __launch_bounds__(256) void gemm_mfma(
    const u16* __restrict__ A, const u16* __restrict__ Bt,
    const float* __restrict__ bias, u16* __restrict__ C,
    int K, int lda)
{
    __shared__ u16 sh[4 * 32 * CS_STRIDE];
    u16* As = sh;
    u16* Bs = sh + 5120;
    const int tid = threadIdx.x;
    const int wave = tid >> 6, lane = tid & 63;
    const int lr = lane & 15, lq = lane >> 4;
    const int bx = blockIdx.x & 3;
    const int by = blockIdx.x >> 2;
    const int row0 = by << 7, col0 = bx << 7;
    const int srow = tid >> 2, skq = tid & 3;

    f32x4 acc[2][8];
#pragma unroll
    for (int mt = 0; mt < 2; mt++)
#pragma unroll
        for (int nt = 0; nt < 8; nt++) acc[mt][nt] = (f32x4){0.f, 0.f, 0.f, 0.f};

    const int arow0 = wave * 32 + lr;
    for (int k0 = 0; k0 < K; k0 += 32) {
        uint4 av[2], bv[2];
#pragma unroll
        for (int it = 0; it < 2; it++) {
            int row = srow + it * 64;
            av[it] = *(const uint4*)(A + (size_t)(row0 + row) * lda + k0 + skq * 8);
            bv[it] = *(const uint4*)(Bt + (size_t)(col0 + row) * K + k0 + skq * 8);
        }
        __syncthreads();
#pragma unroll
        for (int it = 0; it < 2; it++) {
            int row = srow + it * 64;
            *(uint4*)&As[row * 40 + skq * 8] = av[it];
            *(uint4*)&Bs[row * 40 + skq * 8] = bv[it];
        }
        __syncthreads();

        bf16x8 afrag[2], bfrag[8];
        afrag[0] = *(const bf16x8*)&As[(arow0) * 40 + lq * 8];
        afrag[1] = *(const bf16x8*)&As[(arow0 + 16) * 40 + lq * 8];
#pragma unroll
        for (int nt = 0; nt < 8; nt++)
            bfrag[nt] = *(const bf16x8*)&Bs[(nt * 16 + lr) * 40 + lq * 8];
#pragma unroll
        for (int mt = 0; mt < 2; mt++)
#pragma unroll
            for (int nt = 0; nt < 8; nt++)
                acc[mt][nt] = __builtin_amdgcn_mfma_f32_16x16x32_bf16(
                    afrag[mt], bfrag[nt], acc[mt][nt], 0, 0, 0);
    }

    float bl[8];
#pragma unroll
    for (int nt = 0; nt < 8; nt++)
        bl[nt] = bias ? bias[col0 + nt * 16 + lr] : 0.f;

    __syncthreads();
    u16* cs = sh + wave * 32 * CS_STRIDE;
#pragma unroll
    for (int mt = 0; mt < 2; mt++)
#pragma unroll
        for (int nt = 0; nt < 8; nt++)
#pragma unroll
            for (int r = 0; r < 4; r++)
                cs[(mt * 16 + lq * 4 + r) * CS_STRIDE + nt * 16 + lr] =
                    f2bf(acc[mt][nt][r] + bl[nt]);
    __syncthreads();
#pragma unroll
    for (int it = 0; it < 8; it++) {
        int linear = it * 64 + lane;
        int r = linear >> 4, q = linear & 15;
        uint4 v = *(const uint4*)&cs[r * CS_STRIDE + q * 8];
        *(uint4*)(C + (size_t)(row0 + wave * 32 + r) * HID_ + col0 + q * 8) = v;
    }
}

// ---------------------------------------------------------------------------
// Fused GAT layer v2: one block per graph, 8 waves, wave = head, wave-local
// phases, 2 barriers. In-place update of hx (barrier 2 orders reads/writes).
// LDS pool: hT[8][64][72] bf16 | f1s[512] f32 | f2s[512] f32 | c2s[512] f32 |
//           msk[64] u64   = 80,384 B -> 2 blocks/CU.
// ---------------------------------------------------------------------------
#define S_HT 72
__global__ __launch_bounds__(512, 4) void gat_fused(
    u16* __restrict__ hxg, const u16* __restrict__ Wt,
    const float* __restrict__ ag, const uint64_t* __restrict__ masks)
{
    __shared__ __align__(16) u16 pool[40192];
    const int tid = threadIdx.x;
    const int b = blockIdx.x;
    const int wave = tid >> 6, lane = tid & 63;
    const int lr = lane & 15, lq = lane >> 4;
    u16* hTh = pool + wave * 64 * S_HT;
    float* f1s = (float*)(pool + 8 * 64 * S_HT);
    float* f2s = f1s + 512;
    float* c2s = f2s + 512;
    uint64_t* mskl = (uint64_t*)(c2s + 512);

    u16* hxb = hxg + (size_t)b * N_ * HID_;
    if (tid < 64) mskl[tid] = masks[(size_t)b * 64 + tid];
    __syncthreads();   // barrier 1: masks visible

    // ---- projection: h = hx[b] @ W_head, A/B fragments straight from global
    f32x4 acc[4][4];
#pragma unroll
    for (int mt = 0; mt < 4; mt++)
#pragma unroll
        for (int nt = 0; nt < 4; nt++) acc[mt][nt] = (f32x4){0.f, 0.f, 0.f, 0.f};

    const u16* wp = Wt + (size_t)wave * 64 * HID_;
#pragma unroll 4
    for (int kt = 0; kt < 16; kt++) {
        int k0 = kt * 32 + lq * 8;
        bf16x8 af[4];
#pragma unroll
        for (int mt = 0; mt < 4; mt++)
            af[mt] = *(const bf16x8*)(hxb + (size_t)(mt * 16 + lr) * HID_ + k0);
#pragma unroll
        for (int nt = 0; nt < 4; nt++) {
            bf16x8 bfr = *(const bf16x8*)(wp + (size_t)(nt * 16 + lr) * HID_ + k0);
#pragma unroll
            for (int mt = 0; mt < 4; mt++)
                acc[mt][nt] = __builtin_amdgcn_mfma_f32_16x16x32_bf16(
                    af[mt], bfr, acc[mt][nt], 0, 0, 0);
        }
    }

    // ---- transpose h into hTh[d][j] (wave-local), zero pad cols 62/63
#pragma unroll
    for (int nt = 0; nt < 4; nt++) {
        int d = nt * 16 + lr;
#pragma unroll
        for (int mt = 0; mt < 4; mt++) {
            bf16x4 hv;
#pragma unroll
            for (int r = 0; r < 4; r++) hv[r] = (__bf16)acc[mt][nt][r];
            *(bf16x4*)&hTh[d * S_HT + mt * 16 + lq * 4] = hv;
        }
    }
    *(uint32_t*)&hTh[lane * S_HT + 62] = 0;

    // ---- f1/f2 (lane = node j)
    float p1 = 0.f, p2 = 0.f;
    {
        const float* agh = ag + wave * 128;
#pragma unroll
        for (int d = 0; d < 64; d++) {
            float hv = bf2f(hTh[d * S_HT + lane]);
            p1 += hv * agh[d];
            p2 += hv * agh[64 + d];
        }
    }
    f1s[wave * 64 + lane] = p1;
    f2s[wave * 64 + lane] = p2;

    // ---- column softmax stats (lane = column j): c2 = m*log2e + log2(s)
    {
        float m = -9e15f;
        for (int i = 0; i < N_; i++) {
            float z = f2s[wave * 64 + i] + p1;
            z = fmaxf(z, 0.2f * z);
            float zm = ((mskl[i] >> lane) & 1ull) ? z : -9e15f;
            m = fmaxf(m, zm);
        }
        float s = 0.f;
        for (int i = 0; i < N_; i++) {
            float z = f2s[wave * 64 + i] + p1;
            z = fmaxf(z, 0.2f * z);
            float zm = ((mskl[i] >> lane) & 1ull) ? z : -9e15f;
            s += __builtin_amdgcn_exp2f((zm - m) * L2E);
        }
        c2s[wave * 64 + lane] = m * L2E + __builtin_amdgcn_logf(s);
    }

    // ---- hp = P @ h via MFMA; P A-fragments built on the fly
#pragma unroll
    for (int mt = 0; mt < 4; mt++)
#pragma unroll
        for (int nt = 0; nt < 4; nt++) acc[mt][nt] = (f32x4){0.f, 0.f, 0.f, 0.f};

#pragma unroll
    for (int kt = 0; kt < 2; kt++) {
        int j0 = kt * 32 + lq * 8;
        float4 f1a = *(const float4*)&f1s[wave * 64 + j0];
        float4 f1b = *(const float4*)&f1s[wave * 64 + j0 + 4];
        float4 c2a = *(const float4*)&c2s[wave * 64 + j0];
        float4 c2b = *(const float4*)&c2s[wave * 64 + j0 + 4];
        float f1v[8] = {f1a.x, f1a.y, f1a.z, f1a.w, f1b.x, f1b.y, f1b.z, f1b.w};
        float cv[8]  = {c2a.x, c2a.y, c2a.z, c2a.w, c2b.x, c2b.y, c2b.z, c2b.w};
        bf16x8 hb[4];
#pragma unroll
        for (int dt = 0; dt < 4; dt++)
            hb[dt] = *(const bf16x8*)&hTh[(dt * 16 + lr) * S_HT + j0];
#pragma unroll
        for (int it = 0; it < 4; it++) {
            int i = it * 16 + lr;
            float f2i = f2s[wave * 64 + i];
            uint64_t mi = mskl[i];
            bf16x8 pf;
#pragma unroll
            for (int t = 0; t < 8; t++) {
                float z = f2i + f1v[t];
                z = fmaxf(z, 0.2f * z);
                float zm = ((mi >> (j0 + t)) & 1ull) ? z : -9e15f;
                float arg = fminf(zm * L2E - cv[t], 0.f);
                pf[t] = (__bf16)__builtin_amdgcn_exp2f(arg);
            }
#pragma unroll
            for (int dt = 0; dt < 4; dt++)
                acc[it][dt] = __builtin_amdgcn_mfma_f32_16x16x32_bf16(
                    pf, hb[dt], acc[it][dt], 0, 0, 0);
        }
    }

    __syncthreads();   // barrier 2: all proj reads done before in-place writes

    // ---- ELU, stage rows into LDS, coalesced store to hx[b]
#pragma unroll
    for (int it = 0; it < 4; it++)
#pragma unroll
        for (int dt = 0; dt < 4; dt++)
#pragma unroll
            for (int r = 0; r < 4; r++) {
                float v = acc[it][dt][r];
                v = v > 0.f ? v : __builtin_amdgcn_exp2f(v * L2E) - 1.f;
                *(__bf16*)&hTh[(it * 16 + lq * 4 + r) * S_HT + dt * 16 + lr] = (__bf16)v;
            }
#pragma unroll
    for (int rr = 0; rr < 8; rr++) {
        int row = rr * 8 + (lane >> 3);
        if (row < N_) {
            uint4 v = *(const uint4*)&hTh[row * S_HT + (lane & 7) * 8];
            *(uint4*)(hxb + (size_t)row * HID_ + wave * 64 + (lane & 7) * 8) = v;
        }
    }
}

// ---------------------------------------------------------------------------
// pooled[b,:] = sum_n hx[b,n,:]; logits = pooled @ W_out + b_out; log_softmax
// ---------------------------------------------------------------------------
__global__ __launch_bounds__(256) void pool_out(
    const u16* __restrict__ hx, const float* __restrict__ Wout,
    const float* __restrict__ bout, float* __restrict__ out)
{
    __shared__ float pooled[HID_];
    __shared__ float lg[3];
    const int tid = threadIdx.x;
    const int b = blockIdx.x;
    const u16* hb = hx + (size_t)b * N_ * HID_;
    for (int f = tid; f < HID_; f += 256) {
        float s = 0.f;
        for (int n = 0; n < N_; n++) s += bf2f(hb[n * HID_ + f]);
        pooled[f] = s;
    }
    __syncthreads();
    if (tid < 192) {
        int c = tid >> 6, lane = tid & 63;
        float p = 0.f;
        for (int k = lane; k < HID_; k += 64) p += pooled[k] * Wout[k * 3 + c];
        for (int off = 32; off > 0; off >>= 1) p += __shfl_down(p, off, 64);
        if (lane == 0) lg[c] = p + bout[c];
    }
    __syncthreads();
    if (tid == 0) {
        float l0 = lg[0], l1 = lg[1], l2 = lg[2];
        float m = fmaxf(l0, fmaxf(l1, l2));
        float s = __expf(l0 - m) + __expf(l1 - m) + __expf(l2 - m);
        float ls = m + logf(s);
        out[b * 3 + 0] = l0 - ls;
        out[b * 3 + 1] = l1 - ls;
        out[b * 3 + 2] = l2 - ls;
    }
}

// ---------------------------------------------------------------------------
extern "C" void kernel_launch(void* const* d_in, const int* in_sizes, int n_in,
                              void* d_out, int out_size, void* d_ws, size_t ws_size,
                              hipStream_t stream)
{
    const float* x   = (const float*)d_in[0];
    const int*   adj = (const int*)d_in[1];
    const float* bng = (const float*)d_in[2];
    const float* bnb = (const float*)d_in[3];
    const float* bnm = (const float*)d_in[4];
    const float* bnv = (const float*)d_in[5];
    const float* Wm  = (const float*)d_in[6];
    const float* bm  = (const float*)d_in[7];
    const float* Wg  = (const float*)d_in[8];
    const float* ag  = (const float*)d_in[9];
    const float* Wo  = (const float*)d_in[10];
    const float* bo  = (const float*)d_in[11];
    float* out = (float*)d_out;

    // ws layout: xb | hx | masks | wmlp_t | wgat_t  (~166 MB)
    // hx is NOT last: the last graph's padded rows 62/63 read OOB into masks.
    u16* xb = (u16*)d_ws;
    u16* hx = xb + (size_t)M_ * FIN_;
    uint64_t* masks = (uint64_t*)(hx + (size_t)M_ * HID_);
    u16* wmlp_t = (u16*)(masks + (size_t)B_ * 64);
    u16* wgat_t = wmlp_t + (size_t)HID_ * FIN_;

    bn_cast<<<(M_ * (FIN_ / 4) + 255) / 256, 256, 0, stream>>>(x, bng, bnb, bnm, bnv, xb);

    int rep_total = HID_ * FIN_ + LAYERS_ * HID_ * HID_;
    repack_w<<<(rep_total + 255) / 256, 256, 0, stream>>>(Wm, Wg, wmlp_t, wgat_t);

    build_masks<<<B_, 256, 0, stream>>>(adj, masks);

    // MLP: hx = xb @ W_mlp + b_mlp
    gemm_mfma<<<(M_ / 128) * 4, 256, 0, stream>>>(xb, wmlp_t, bm, hx, FIN_, FIN_);

    for (int l = 0; l < LAYERS_; l++) {
        gat_fused<<<B_, 512, 0, stream>>>(
            hx, wgat_t + (size_t)l * HID_ * HID_,
            ag + (size_t)l * HEADS_ * 2 * FOUT_, masks);
    }
    pool_out<<<B_, 256, 0, stream>>>(hx, Wo, bo, out);
}